// Round 13
// baseline (340.998 us; speedup 1.0000x reference)
//
#include <hip/hip_runtime.h>
#include <hip/hip_bf16.h>
#include <stdint.h>

// Problem constants
#define NQ    2304          // H*W = 48*48 tokens
#define MROWS 4608          // B*NQ
#define DIMC  768
#define NHEAD 12
#define HEADS 24            // B*NH
#define HD    64

typedef unsigned int uint;
typedef unsigned short u16;
typedef __attribute__((ext_vector_type(8))) short s16x8;   // 8 bf16 = 4 VGPR
typedef __attribute__((ext_vector_type(4))) float f32x4;   // mfma acc

#define MFMA16(a, b, c) __builtin_amdgcn_mfma_f32_16x16x32_bf16((a), (b), (c), 0, 0, 0)
#define LOG2E 1.44269504f

static __device__ __forceinline__ float bfbits2f(uint u) {
  union { uint i; float f; } c; c.i = u << 16; return c.f;
}
static __device__ __forceinline__ u16 f2bf(float f) {
  __hip_bfloat16 h = __float2bfloat16(f);
  union { __hip_bfloat16 h; u16 u; } c; c.h = h; return c.u;
}
static __device__ __forceinline__ u16 f2h(float f) {
  union { _Float16 h; u16 u; } c; c.h = (_Float16)f; return c.u;
}
static __device__ __forceinline__ float h2f(u16 u) {
  union { u16 u; _Float16 h; } c; c.u = u; return (float)c.h;
}
// 2^x via the HW transcendental (no pre-multiply). Exact fallback.
static __device__ __forceinline__ float fexp2(float x) {
#if __has_builtin(__builtin_amdgcn_exp2f)
  return __builtin_amdgcn_exp2f(x);
#else
  return __expf(x * 0.69314718f);
#endif
}
static __device__ __forceinline__ void dec8(uint4 p, float* f) {
  f[0] = bfbits2f(p.x & 0xFFFFu); f[1] = bfbits2f(p.x >> 16);
  f[2] = bfbits2f(p.y & 0xFFFFu); f[3] = bfbits2f(p.y >> 16);
  f[4] = bfbits2f(p.z & 0xFFFFu); f[5] = bfbits2f(p.z >> 16);
  f[6] = bfbits2f(p.w & 0xFFFFu); f[7] = bfbits2f(p.w >> 16);
}
// dual-dtype 8-element load -> fp32 (bf=1: bf16, bf=0: fp32)
static __device__ __forceinline__ void ld8(const void* p, size_t idx, int bf, float* f) {
  if (bf) { dec8(*(const uint4*)((const u16*)p + idx), f); }
  else {
    const float4* q = (const float4*)((const float*)p + idx);
    float4 a = q[0], b = q[1];
    f[0] = a.x; f[1] = a.y; f[2] = a.z; f[3] = a.w;
    f[4] = b.x; f[5] = b.y; f[6] = b.z; f[7] = b.w;
  }
}
static __device__ __forceinline__ float ld1(const void* p, size_t idx, int bf) {
  return bf ? bfbits2f(((const u16*)p)[idx]) : ((const float*)p)[idx];
}
// dual-dtype 8-element load -> packed bf16 (uint4)
static __device__ __forceinline__ uint4 ld8_to_bf(const void* p, size_t idx, int bf) {
  if (bf) return *(const uint4*)((const u16*)p + idx);
  float f[8]; ld8(p, idx, 0, f);
  uint4 u;
  u.x = (uint)f2bf(f[0]) | ((uint)f2bf(f[1]) << 16);
  u.y = (uint)f2bf(f[2]) | ((uint)f2bf(f[3]) << 16);
  u.z = (uint)f2bf(f[4]) | ((uint)f2bf(f[5]) << 16);
  u.w = (uint)f2bf(f[6]) | ((uint)f2bf(f[7]) << 16);
  return u;
}
// async 16B global->LDS (dest: wave-uniform base, HW adds lane*16)
static __device__ __forceinline__ void gll16(const u16* g, u16* l) {
  __builtin_amdgcn_global_load_lds(
      (const __attribute__((address_space(1))) unsigned int*)g,
      (__attribute__((address_space(3))) unsigned int*)l, 16, 0, 0);
}

// ---------------------------------------------------------------------------
// K0: dtype detector (verified).
// ---------------------------------------------------------------------------
__global__ __launch_bounds__(256) void detect_k(const u16* __restrict__ x,
                                                int* __restrict__ mode) {
  __shared__ int wsum[4];
  int t = threadIdx.x;
  int cnt = 0;
  for (int i = 0; i < 8; ++i) {
    uint u = x[(size_t)(t * 8 + i) * 2];
    uint e = (u >> 7) & 0xFFu;
    uint mag = u & 0x7FFFu;
    if (mag == 0 || (e >= 113 && e <= 133)) cnt++;
  }
#pragma unroll
  for (int d = 1; d < 64; d <<= 1) cnt += __shfl_xor(cnt, d);
  if ((t & 63) == 0) wsum[t >> 6] = cnt;
  __syncthreads();
  if (t == 0) mode[0] = ((wsum[0] + wsum[1] + wsum[2] + wsum[3]) > 1024) ? 1 : 0;
}

// ---------------------------------------------------------------------------
// K0b: convert x / qkv_w / proj_w to bf16 (verified round 11).
// ---------------------------------------------------------------------------
#define NX8 442368u   // 4608*768/8
#define NW8 221184u   // 2304*768/8
#define NP8 73728u    // 768*768/8
__global__ __launch_bounds__(256) void convert_k(
    const void* __restrict__ x, const void* __restrict__ qkvw,
    const void* __restrict__ pw, const int* __restrict__ mode,
    u16* __restrict__ xb, u16* __restrict__ wb, u16* __restrict__ pwb)
{
  const int bf = mode[0];
  uint i8 = blockIdx.x * 256 + threadIdx.x;
  if (i8 < NX8) {
    *(uint4*)(xb + (size_t)i8 * 8) = ld8_to_bf(x, (size_t)i8 * 8, bf);
  } else if (i8 < NX8 + NW8) {
    size_t j = i8 - NX8;
    *(uint4*)(wb + j * 8) = ld8_to_bf(qkvw, j * 8, bf);
  } else if (i8 < NX8 + NW8 + NP8) {
    size_t j = i8 - NX8 - NW8;
    *(uint4*)(pwb + j * 8) = ld8_to_bf(pw, j * 8, bf);
  }
}

// ---------------------------------------------------------------------------
// K1: QKV projection — round 13: gll16 staging (r12, verified) + FUSED V^T.
// V-column blocks (blockIdx.x 12-17) transpose their 128x128 tile through
// LDS in two 64-col halves and store V^T [bh][d][n] coalesced. vtrans_k
// is deleted. Q/K epilogue unchanged.
// ---------------------------------------------------------------------------
__global__ __launch_bounds__(256) void qkv_gemm_k(
    const u16* __restrict__ Xb, const u16* __restrict__ Wb,
    const void* __restrict__ Bq, const int* __restrict__ mode,
    u16* __restrict__ Q, u16* __restrict__ K, u16* __restrict__ Vt)
{
  __shared__ __align__(16) u16 As[128][32];
  __shared__ __align__(16) u16 Bs[128][32];
  __shared__ __align__(16) u16 Ts[128][72];   // V^T staging (idle for Q/K blocks)
  const int bf = mode[0];
  const int t = threadIdx.x;
  const int w = t >> 6, lane = t & 63, l15 = t & 15, quad = (t >> 4) & 3;
  const int wr = w >> 1, wc = w & 1;
  const int row0 = blockIdx.y << 7, col0 = blockIdx.x << 7;
  const int r4 = lane >> 2, c8 = (lane & 3) << 3;   // staging lane map

  f32x4 zero4 = {0.f, 0.f, 0.f, 0.f};
  f32x4 acc[4][4];
#pragma unroll
  for (int i = 0; i < 4; ++i)
#pragma unroll
    for (int j = 0; j < 4; ++j) acc[i][j] = zero4;

  for (int kt = 0; kt < DIMC; kt += 32) {
    __syncthreads();
    gll16(Xb + (size_t)(row0 + (w << 5) + r4) * DIMC + kt + c8,      &As[(w << 5)][0]);
    gll16(Xb + (size_t)(row0 + (w << 5) + 16 + r4) * DIMC + kt + c8, &As[(w << 5) + 16][0]);
    gll16(Wb + (size_t)(col0 + (w << 5) + r4) * DIMC + kt + c8,      &Bs[(w << 5)][0]);
    gll16(Wb + (size_t)(col0 + (w << 5) + 16 + r4) * DIMC + kt + c8, &Bs[(w << 5) + 16][0]);
    __syncthreads();
    s16x8 af[4], bfr[4];
#pragma unroll
    for (int i = 0; i < 4; ++i)
      af[i] = *(const s16x8*)&As[(wr << 6) + (i << 4) + l15][quad << 3];
#pragma unroll
    for (int j = 0; j < 4; ++j)
      bfr[j] = *(const s16x8*)&Bs[(wc << 6) + (j << 4) + l15][quad << 3];
#pragma unroll
    for (int i = 0; i < 4; ++i)
#pragma unroll
      for (int j = 0; j < 4; ++j)
        acc[i][j] = MFMA16(af[i], bfr[j], acc[i][j]);
  }

  if (blockIdx.x < 12) {
    // Q/K path: scatter per element (verified)
#pragma unroll
    for (int jt = 0; jt < 4; ++jt) {
      int col = col0 + (wc << 6) + (jt << 4) + l15;     // 0..1535
      int which = col / DIMC;
      int rem = col - which * DIMC;
      int head = rem >> 6, d = rem & 63;
      float bv = ld1(Bq, col, bf);
      u16* dst = (which == 0) ? Q : K;
#pragma unroll
      for (int i = 0; i < 4; ++i)
#pragma unroll
        for (int r = 0; r < 4; ++r) {
          int mrow = row0 + (wr << 6) + (i << 4) + (quad << 2) + r;
          int b_ = (mrow >= NQ) ? 1 : 0;
          int n = mrow - b_ * NQ;
          dst[(((size_t)(b_ * NHEAD + head)) * NQ + n) * HD + d] = f2bf(acc[i][jt][r] + bv);
        }
    }
  } else {
    // V path: transpose to Vt [bh][d][n] via LDS, two 64-col halves.
    // row block spans a single batch (2304 % 128 == 0).
    int b_ = (row0 >= NQ) ? 1 : 0;
    int n0 = row0 - b_ * NQ;
#pragma unroll
    for (int h = 0; h < 2; ++h) {
      if (wc == h) {
#pragma unroll
        for (int jt = 0; jt < 4; ++jt) {
          int coll = (jt << 4) + l15;                  // 0..63 within half
          float bv = ld1(Bq, col0 + (h << 6) + coll, bf);
#pragma unroll
          for (int i = 0; i < 4; ++i)
#pragma unroll
            for (int r = 0; r < 4; ++r) {
              int tok = (wr << 6) + (i << 4) + (quad << 2) + r;   // 0..127
              Ts[tok][coll] = f2bf(acc[i][jt][r] + bv);
            }
        }
      }
      __syncthreads();
      // this half is exactly one head: head = (col0-1536)/64 + h
      int head = ((col0 - 1536) >> 6) + h;
      u16* dst = Vt + ((size_t)(b_ * NHEAD + head) * HD) * NQ + n0;
      int d = t >> 2, ch = (t & 3) << 5;               // 64 d x 4 token-chunks
#pragma unroll
      for (int c4 = 0; c4 < 4; ++c4) {
        u16 tmp[8];
#pragma unroll
        for (int j = 0; j < 8; ++j) tmp[j] = Ts[ch + (c4 << 3) + j][d];
        *(uint4*)(dst + (size_t)d * NQ + ch + (c4 << 3)) = *(uint4*)tmp;
      }
      __syncthreads();
    }
  }
}

// ---------------------------------------------------------------------------
// K1b: bias precompute as MFMA GEMM (round 7, verified). Round-13 change:
// output pre-multiplied by log2(e) so attn can use v_exp (2^x) directly.
// ---------------------------------------------------------------------------
__global__ __launch_bounds__(256) void bias_gemm_k(
    const u16* __restrict__ Qw,
    const void* __restrict__ rph, const void* __restrict__ rpw,
    const int* __restrict__ mode,
    u16* __restrict__ Bh_g, u16* __restrict__ Bw_g)
{
  __shared__ __align__(16) u16 As[128][72];
  __shared__ __align__(16) u16 Bs[192][72];
  const int bf = mode[0];
  const int t = threadIdx.x;
  const int w = t >> 6, l15 = t & 15, quad = (t >> 4) & 3;
  const int wr = w >> 1, wc = w & 1;
  const int blk = blockIdx.x;          // 0..431
  const int bhd = blk / 18;
  const int row0 = (blk - bhd * 18) << 7;

  {
    int lr = t >> 1, lk = (t & 1) << 5;
    const u16* src = Qw + ((size_t)bhd * NQ + row0 + lr) * HD + lk;
    *(uint4*)&As[lr][lk]      = *(const uint4*)(src);
    *(uint4*)&As[lr][lk + 8]  = *(const uint4*)(src + 8);
    *(uint4*)&As[lr][lk + 16] = *(const uint4*)(src + 16);
    *(uint4*)&As[lr][lk + 24] = *(const uint4*)(src + 24);
  }
  for (int e = t; e < 384; e += 256) {
    int row = e >> 1, k32 = (e & 1) << 5;
    int tab = (row >= 96) ? 1 : 0;
    int r2 = row - (tab ? 96 : 0);
    if (r2 > 94) r2 = 0;
    const void* src = tab ? rpw : rph;
    *(uint4*)&Bs[row][k32]      = ld8_to_bf(src, (size_t)r2 * HD + k32, bf);
    *(uint4*)&Bs[row][k32 + 8]  = ld8_to_bf(src, (size_t)r2 * HD + k32 + 8, bf);
    *(uint4*)&Bs[row][k32 + 16] = ld8_to_bf(src, (size_t)r2 * HD + k32 + 16, bf);
    *(uint4*)&Bs[row][k32 + 24] = ld8_to_bf(src, (size_t)r2 * HD + k32 + 24, bf);
  }
  __syncthreads();

  f32x4 zero4 = {0.f, 0.f, 0.f, 0.f};
  f32x4 acc[4][6];
#pragma unroll
  for (int i = 0; i < 4; ++i)
#pragma unroll
    for (int j = 0; j < 6; ++j) acc[i][j] = zero4;

#pragma unroll
  for (int ks = 0; ks < 2; ++ks) {
    s16x8 af[4], bfr[6];
#pragma unroll
    for (int i = 0; i < 4; ++i)
      af[i] = *(const s16x8*)&As[(wr << 6) + (i << 4) + l15][(ks << 5) + (quad << 3)];
#pragma unroll
    for (int j = 0; j < 6; ++j)
      bfr[j] = *(const s16x8*)&Bs[wc * 96 + (j << 4) + l15][(ks << 5) + (quad << 3)];
#pragma unroll
    for (int i = 0; i < 4; ++i)
#pragma unroll
      for (int j = 0; j < 6; ++j)
        acc[i][j] = MFMA16(af[i], bfr[j], acc[i][j]);
  }

#pragma unroll
  for (int jt = 0; jt < 6; ++jt) {
    int col = wc * 96 + (jt << 4) + l15;     // 0..191
    int tab = (col >= 96) ? 1 : 0;
    int j = col - (tab ? 96 : 0);
    if (j >= 95) continue;
    u16* dstT = tab ? Bw_g : Bh_g;
#pragma unroll
    for (int i = 0; i < 4; ++i)
#pragma unroll
      for (int r = 0; r < 4; ++r) {
        int n = row0 + (wr << 6) + (i << 4) + (quad << 2) + r;
        int qh = (n * 10923) >> 19;
        int coord = tab ? (n - qh * 48) : qh;
        int c = coord + 47 - j;
        if (c >= 0 && c < 48)
          dstT[((size_t)bhd * 48 + c) * NQ + n] = f2h(acc[i][jt][r] * LOG2E);
      }
  }
}

// ---------------------------------------------------------------------------
// K2: MFMA flash attention, round 13 = r12 (152.7 µs verified) +
//  (a) s_setprio(1) around MFMA clusters (guide T5: +4-7% on attn with
//      phase-shifted independent waves — exactly this structure)
//  (b) exp2 folding: tables pre-x log2e, scale' = 0.125*log2e, v_exp direct.
// ---------------------------------------------------------------------------
#define ATILE(KB, KN, T0, PREF, KM) do {                                      \
    f32x4 acc_s[2][4];                                                        \
    __builtin_amdgcn_s_setprio(1);                                            \
    _Pragma("unroll")                                                         \
    for (int nc = 0; nc < 4; ++nc) {                                          \
      f32x4 a0 = MFMA16(KB[2*nc], qa0[0], zero4);                             \
      acc_s[0][nc] = MFMA16(KB[2*nc+1], qa1[0], a0);                          \
      f32x4 a1 = MFMA16(KB[2*nc], qa0[1], zero4);                             \
      acc_s[1][nc] = MFMA16(KB[2*nc+1], qa1[1], a1);                          \
    }                                                                         \
    __builtin_amdgcn_s_setprio(0);                                            \
    if (PREF) {                                                               \
      _Pragma("unroll")                                                       \
      for (int nc = 0; nc < 4; ++nc) {                                        \
        const u16* kp_ = kbase + (size_t)((T0) + 64 + (nc << 4) + l15) * HD + (quad << 3); \
        KN[2*nc]   = *(const s16x8*)(kp_);                                    \
        KN[2*nc+1] = *(const s16x8*)(kp_ + 32);                               \
      }                                                                       \
    }                                                                         \
    int kh0 = ((T0) * 10923) >> 19;                                           \
    int thr = (kh0 + 1) * 48 - (T0);                                          \
    uint Wq[2][8];                                                            \
    _Pragma("unroll")                                                         \
    for (int g = 0; g < 2; ++g) {                                             \
      int qrl = (w << 5) + (g << 4) + l15;                                    \
      float bh0v = h2f(BhL[kh0][qrl]);                                        \
      float bh1v = h2f(BhL[kh0 + 1][qrl]);                                    \
      float sum = 0.f;                                                        \
      _Pragma("unroll")                                                       \
      for (int nc = 0; nc < 4; ++nc) {                                        \
        int bnc = (KM) + (nc << 4);                                           \
        bnc = (bnc >= 48) ? bnc - 48 : bnc;                                   \
        uint2 pv = *(const uint2*)&BwL[qrl][bnc + (quad << 2)];               \
        float b0 = h2f((u16)(pv.x & 0xFFFFu));                                \
        float b1 = h2f((u16)(pv.x >> 16));                                    \
        float b2 = h2f((u16)(pv.y & 0xFFFFu));                                \
        float b3 = h2f((u16)(pv.y >> 16));                                    \
        int kl = (nc << 4) + (quad << 2);                                     \
        float e0 = fexp2(fmaf(acc_s[g][nc][0], scl2, ((kl     >= thr) ? bh1v : bh0v)) + b0); \
        float e1 = fexp2(fmaf(acc_s[g][nc][1], scl2, ((kl + 1 >= thr) ? bh1v : bh0v)) + b1); \
        float e2 = fexp2(fmaf(acc_s[g][nc][2], scl2, ((kl + 2 >= thr) ? bh1v : bh0v)) + b2); \
        float e3 = fexp2(fmaf(acc_s[g][nc][3], scl2, ((kl + 3 >= thr) ? bh1v : bh0v)) + b3); \
        sum += (e0 + e1) + (e2 + e3);                                         \
        Wq[g][2*nc]   = (uint)f2bf(e0) | ((uint)f2bf(e1) << 16);              \
        Wq[g][2*nc+1] = (uint)f2bf(e2) | ((uint)f2bf(e3) << 16);              \
      }                                                                       \
      l_st[g] += sum;                                                         \
    }                                                                         \
    _Pragma("unroll")                                                         \
    for (int h = 0; h < 2; ++h) {                                             \
      s16x8 vb[4];                                                            \
      _Pragma("unroll")                                                       \
      for (int nc = 0; nc < 4; ++nc)                                          \
        vb[nc] = *(const s16x8*)(vtbase + (size_t)((nc << 4) + l15) * NQ      \
                                 + (T0) + (h << 5) + (quad << 3));            \
      _Pragma("unroll")                                                       \
      for (int g = 0; g < 2; ++g) {                                           \
        uint e0 = __shfl(Wq[g][4*h+0], srcA), e1 = __shfl(Wq[g][4*h+1], srcA); \
        uint e2 = __shfl(Wq[g][4*h+2], srcA), e3 = __shfl(Wq[g][4*h+3], srcA); \
        uint g0 = __shfl(Wq[g][4*h+0], srcB), g1 = __shfl(Wq[g][4*h+1], srcB); \
        uint g2 = __shfl(Wq[g][4*h+2], srcB), g3 = __shfl(Wq[g][4*h+3], srcB); \
        union { uint u[4]; s16x8 v; } pf;                                     \
        pf.u[0] = hi ? e2 : e0; pf.u[1] = hi ? e3 : e1;                       \
        pf.u[2] = hi ? g2 : g0; pf.u[3] = hi ? g3 : g1;                       \
        __builtin_amdgcn_s_setprio(1);                                        \
        _Pragma("unroll")                                                     \
        for (int nc = 0; nc < 4; ++nc)                                        \
          acc_o[g][nc] = MFMA16(pf.v, vb[nc], acc_o[g][nc]);                  \
        __builtin_amdgcn_s_setprio(0);                                        \
      }                                                                       \
    }                                                                         \
  } while (0)

__global__ __launch_bounds__(256) void attn_k(
    const u16* __restrict__ Qw, const u16* __restrict__ Kw,
    const u16* __restrict__ Vtg,
    const u16* __restrict__ Bh_g, const u16* __restrict__ Bw_g,
    int S, float* __restrict__ Opart, float* __restrict__ Lpart,
    u16* __restrict__ Aout)
{
  __shared__ __align__(16) u16 BhL[48][128];  // fp16 [kh][local qrow]  (x log2e)
  __shared__ __align__(16) u16 BwL[128][52];  // fp16 [local qrow][kw]  (x log2e)

  const int bid = blockIdx.x;
  const int xcd = bid & 7;
  const int local = bid >> 3;            // [0, 54*S)
  const int per_head = 18 * S;
  const int head_l = local / per_head;   // 0..2
  const int rem = local - head_l * per_head;
  const int qb = rem / S;                // 0..17 (128-row q block)
  const int z = rem - qb * S;
  const int bhd = xcd * 3 + head_l;
  const int q0 = qb << 7;
  const int span = NQ / S;               // 2304/1152/768 — all mult of 128
  const int kt_lo = z * span, kt_hi = kt_lo + span;

  const int t = threadIdx.x;
  const int w = t >> 6, l15 = t & 15, quad = (t >> 4) & 3;
  const float scl2 = 0.125f * LOG2E;     // scale folded with log2(e)

  const u16* kbase  = Kw  + (size_t)bhd * NQ * HD;
  const u16* vtbase = Vtg + (size_t)bhd * HD * NQ;
  const int q0w = q0 + (w << 5);         // wave's 32-row base (global token)

  for (int e = t; e < 768; e += 256) {
    int c = e >> 4;                       // kh/kw 0..47
    int off = (e & 15) << 3;              // qrow 0..120 step 8
    size_t gi = ((size_t)bhd * 48 + c) * NQ + q0 + off;
    *(uint4*)&BhL[c][off] = *(const uint4*)(Bh_g + gi);
    uint4 wv = *(const uint4*)(Bw_g + gi);
    u16 vals[8];
    vals[0] = wv.x & 0xFFFFu; vals[1] = wv.x >> 16;
    vals[2] = wv.y & 0xFFFFu; vals[3] = wv.y >> 16;
    vals[4] = wv.z & 0xFFFFu; vals[5] = wv.z >> 16;
    vals[6] = wv.w & 0xFFFFu; vals[7] = wv.w >> 16;
#pragma unroll
    for (int j = 0; j < 8; ++j) BwL[off + j][c] = vals[j];
  }

  s16x8 qa0[2], qa1[2];
#pragma unroll
  for (int g = 0; g < 2; ++g) {
    const u16* qfrag = Qw + ((size_t)bhd * NQ + q0w + (g << 4) + l15) * HD + (quad << 3);
    qa0[g] = *(const s16x8*)(qfrag);
    qa1[g] = *(const s16x8*)(qfrag + 32);
  }

  s16x8 kbA[8], kbB[8];
#pragma unroll
  for (int nc = 0; nc < 4; ++nc) {
    const u16* kp = kbase + (size_t)(kt_lo + (nc << 4) + l15) * HD + (quad << 3);
    kbA[2*nc]   = *(const s16x8*)(kp);
    kbA[2*nc+1] = *(const s16x8*)(kp + 32);
  }

  __syncthreads();   // bias tables visible

  f32x4 zero4 = {0.f, 0.f, 0.f, 0.f};
  f32x4 acc_o[2][4];
#pragma unroll
  for (int g = 0; g < 2; ++g)
#pragma unroll
    for (int nc = 0; nc < 4; ++nc) acc_o[g][nc] = zero4;
  float l_st[2] = {0.f, 0.f};
  const int srcA = ((quad & 1) << 5) + l15;
  const int srcB = srcA + 16;
  const int hi = quad >> 1;
  int km = 0;

  for (int kt0 = kt_lo; kt0 < kt_hi; kt0 += 128) {
    ATILE(kbA, kbB, kt0, 1, km);
    km += 16; if (km >= 48) km -= 48;
    int pref2 = (kt0 + 128) < kt_hi;
    ATILE(kbB, kbA, kt0 + 64, pref2, km);
    km += 16; if (km >= 48) km -= 48;
  }

#pragma unroll
  for (int g = 0; g < 2; ++g) {
    float lg = l_st[g];
    lg += __shfl_xor(lg, 16);
    lg += __shfl_xor(lg, 32);
    if (S > 1) {
      float* Op = Opart + ((size_t)(z * HEADS + bhd) * NQ + q0) * HD;
#pragma unroll
      for (int r = 0; r < 4; ++r) {
        int row = (w << 5) + (g << 4) + (quad << 2) + r;
#pragma unroll
        for (int nc = 0; nc < 4; ++nc)
          Op[(size_t)row * HD + (nc << 4) + l15] = acc_o[g][nc][r];
      }
      if (quad == 0)
        Lpart[(size_t)(z * HEADS + bhd) * NQ + q0w + (g << 4) + l15] = lg;
    } else {
      int b_ = bhd / NHEAD, head = bhd - b_ * NHEAD;
      float invl = 1.f / lg;
      int bsrc = (quad << 4) + (quad << 2);
#pragma unroll
      for (int r = 0; r < 4; ++r) {
        float inv = __shfl(invl, bsrc + r);
        int token = q0 + (w << 5) + (g << 4) + (quad << 2) + r;
        u16* dst = Aout + ((size_t)b_ * NQ + token) * DIMC + (head << 6);
#pragma unroll
        for (int nc = 0; nc < 4; ++nc)
          dst[(nc << 4) + l15] = f2bf(acc_o[g][nc][r] * inv);
      }
    }
  }
}

// ---------------------------------------------------------------------------
// K2b: combine split-K partials (verified).
// ---------------------------------------------------------------------------
__global__ __launch_bounds__(256) void combine_k(
    const float* __restrict__ Op, const float* __restrict__ Lp,
    int S, u16* __restrict__ Aout)
{
  int idx = blockIdx.x * 256 + threadIdx.x;   // 0 .. 884735
  int m = idx / 192;
  int cq = idx - m * 192;
  int ccol = cq << 2;
  int head = ccol >> 6, d0 = ccol & 63;
  int b_ = (m >= NQ) ? 1 : 0;
  int n = m - b_ * NQ;
  int bh = b_ * NHEAD + head;
  float ox = 0.f, oy = 0.f, oz = 0.f, ow = 0.f, ls = 0.f;
  for (int zz = 0; zz < S; ++zz) {
    const float* ob = Op + ((size_t)(zz * HEADS + bh) * NQ + n) * HD + d0;
    float4 v = *(const float4*)ob;
    ox += v.x; oy += v.y; oz += v.z; ow += v.w;
    ls += Lp[(size_t)(zz * HEADS + bh) * NQ + n];
  }
  float inv = 1.f / ls;
  u16* dst = Aout + (size_t)m * DIMC + ccol;
  dst[0] = f2bf(ox * inv); dst[1] = f2bf(oy * inv);
  dst[2] = f2bf(oz * inv); dst[3] = f2bf(ow * inv);
}

// ---------------------------------------------------------------------------
// K3: output projection — gll16 staging (r12, verified).
// ---------------------------------------------------------------------------
__global__ __launch_bounds__(256) void proj_gemm_k(
    const u16* __restrict__ A, const u16* __restrict__ Wb,
    const void* __restrict__ Bp, const int* __restrict__ mode,
    void* __restrict__ Out)
{
  __shared__ __align__(16) u16 As[128][32];
  __shared__ __align__(16) u16 Bs[128][32];
  const int bf = mode[0];
  const int t = threadIdx.x;
  const int w = t >> 6, lane = t & 63, l15 = t & 15, quad = (t >> 4) & 3;
  const int wr = w >> 1, wc = w & 1;
  const int row0 = blockIdx.y << 7, col0 = blockIdx.x << 7;
  const int r4 = lane >> 2, c8 = (lane & 3) << 3;

  f32x4 zero4 = {0.f, 0.f, 0.f, 0.f};
  f32x4 acc[4][4];
#pragma unroll
  for (int i = 0; i < 4; ++i)
#pragma unroll
    for (int j = 0; j < 4; ++j) acc[i][j] = zero4;

  for (int kt = 0; kt < DIMC; kt += 32) {
    __syncthreads();
    gll16(A + (size_t)(row0 + (w << 5) + r4) * DIMC + kt + c8,       &As[(w << 5)][0]);
    gll16(A + (size_t)(row0 + (w << 5) + 16 + r4) * DIMC + kt + c8,  &As[(w << 5) + 16][0]);
    gll16(Wb + (size_t)(col0 + (w << 5) + r4) * DIMC + kt + c8,      &Bs[(w << 5)][0]);
    gll16(Wb + (size_t)(col0 + (w << 5) + 16 + r4) * DIMC + kt + c8, &Bs[(w << 5) + 16][0]);
    __syncthreads();
    s16x8 af[4], bfr[4];
#pragma unroll
    for (int i = 0; i < 4; ++i)
      af[i] = *(const s16x8*)&As[(wr << 6) + (i << 4) + l15][quad << 3];
#pragma unroll
    for (int j = 0; j < 4; ++j)
      bfr[j] = *(const s16x8*)&Bs[(wc << 6) + (j << 4) + l15][quad << 3];
#pragma unroll
    for (int i = 0; i < 4; ++i)
#pragma unroll
      for (int j = 0; j < 4; ++j)
        acc[i][j] = MFMA16(af[i], bfr[j], acc[i][j]);
  }

#pragma unroll
  for (int jt = 0; jt < 4; ++jt) {
    int col = col0 + (wc << 6) + (jt << 4) + l15;
    float bv = ld1(Bp, col, bf);
#pragma unroll
    for (int i = 0; i < 4; ++i)
#pragma unroll
      for (int r = 0; r < 4; ++r) {
        int mrow = row0 + (wr << 6) + (i << 4) + (quad << 2) + r;
        float val = acc[i][jt][r] + bv;
        size_t off = (size_t)mrow * DIMC + col;
        if (bf) ((u16*)Out)[off] = f2bf(val);
        else    ((float*)Out)[off] = val;
      }
  }
}

// ---------------------------------------------------------------------------
extern "C" void kernel_launch(void* const* d_in, const int* in_sizes, int n_in,
                              void* d_out, int out_size, void* d_ws, size_t ws_size,
                              hipStream_t stream)
{
  const void* x    = d_in[0];   // (2,48,48,768)
  const void* rph  = d_in[1];   // (95,64)
  const void* rpw  = d_in[2];   // (95,64)
  const void* qkvw = d_in[3];   // (2304,768)
  const void* qkvb = d_in[4];   // (2304,)
  const void* pw   = d_in[5];   // (768,768)
  const void* pb   = d_in[6];   // (768,)

  int* mode = (int*)d_ws;
  const size_t qkv_elems = (size_t)HEADS * NQ * HD;   // 3,538,944
  const size_t NXe = (size_t)MROWS * DIMC;            // 3,538,944
  const size_t NWe = (size_t)3 * DIMC * DIMC;         // 1,769,472
  const size_t NPe = (size_t)DIMC * DIMC;             //   589,824
  u16* q    = (u16*)((char*)d_ws + 16);
  u16* k    = q + qkv_elems;
  u16* vt   = k + qkv_elems;
  u16* aout = vt + qkv_elems;
  u16* pwb  = aout + qkv_elems;
  const size_t biasElems = (size_t)HEADS * 48 * NQ;   // 2,654,208 per table
  u16* bh_g = pwb + NPe;
  u16* bw_g = bh_g + biasElems;
  char* R   = (char*)(bw_g + biasElems);
  const size_t baseR = (size_t)((char*)R - (char*)d_ws);
  u16* xb = (u16*)R;
  u16* wb = xb + NXe;
  const size_t needXW = (NXe + NWe) * 2;              // 10,616,832
  const size_t perO = (size_t)HEADS * NQ * HD * 4;    // 14,155,776
  const size_t perL = (size_t)HEADS * NQ * 4;         //    221,184

  int S = 1;
  size_t n3 = 3 * (perO + perL), n2 = 2 * (perO + perL);
  if (ws_size >= baseR + (n3 > needXW ? n3 : needXW)) S = 3;
  else if (ws_size >= baseR + (n2 > needXW ? n2 : needXW)) S = 2;
  float* opart = (float*)R;
  float* lpart = (float*)(R + (size_t)S * perO);

  detect_k<<<1, 256, 0, stream>>>((const u16*)x, mode);
  convert_k<<<dim3(2880), 256, 0, stream>>>(x, qkvw, pw, mode, xb, wb, pwb);
  qkv_gemm_k<<<dim3(18, 36), 256, 0, stream>>>(xb, wb, qkvb, mode, q, k, vt);
  bias_gemm_k<<<dim3(432), 256, 0, stream>>>(q, rph, rpw, mode, bh_g, bw_g);
  attn_k<<<dim3(432 * S), 256, 0, stream>>>(q, k, vt, bh_g, bw_g,
                                            S, opart, lpart, aout);
  if (S > 1)
    combine_k<<<dim3(3456), 256, 0, stream>>>(opart, lpart, S, aout);
  proj_gemm_k<<<dim3(6, 36), 256, 0, stream>>>(aout, pwb, pb, mode, d_out);
}

// Round 14
// 330.982 us; speedup vs baseline: 1.0303x; 1.0303x over previous
//
#include <hip/hip_runtime.h>
#include <hip/hip_bf16.h>
#include <stdint.h>

// Problem constants
#define NQ    2304          // H*W = 48*48 tokens
#define MROWS 4608          // B*NQ
#define DIMC  768
#define NHEAD 12
#define HEADS 24            // B*NH
#define HD    64

typedef unsigned int uint;
typedef unsigned short u16;
typedef __attribute__((ext_vector_type(8))) short s16x8;   // 8 bf16 = 4 VGPR
typedef __attribute__((ext_vector_type(4))) float f32x4;   // mfma acc

#define MFMA16(a, b, c) __builtin_amdgcn_mfma_f32_16x16x32_bf16((a), (b), (c), 0, 0, 0)

static __device__ __forceinline__ float bfbits2f(uint u) {
  union { uint i; float f; } c; c.i = u << 16; return c.f;
}
static __device__ __forceinline__ u16 f2bf(float f) {
  __hip_bfloat16 h = __float2bfloat16(f);
  union { __hip_bfloat16 h; u16 u; } c; c.h = h; return c.u;
}
static __device__ __forceinline__ u16 f2h(float f) {
  union { _Float16 h; u16 u; } c; c.h = (_Float16)f; return c.u;
}
static __device__ __forceinline__ float h2f(u16 u) {
  union { u16 u; _Float16 h; } c; c.u = u; return (float)c.h;
}
static __device__ __forceinline__ void dec8(uint4 p, float* f) {
  f[0] = bfbits2f(p.x & 0xFFFFu); f[1] = bfbits2f(p.x >> 16);
  f[2] = bfbits2f(p.y & 0xFFFFu); f[3] = bfbits2f(p.y >> 16);
  f[4] = bfbits2f(p.z & 0xFFFFu); f[5] = bfbits2f(p.z >> 16);
  f[6] = bfbits2f(p.w & 0xFFFFu); f[7] = bfbits2f(p.w >> 16);
}
// dual-dtype 8-element load -> fp32 (bf=1: bf16, bf=0: fp32)
static __device__ __forceinline__ void ld8(const void* p, size_t idx, int bf, float* f) {
  if (bf) { dec8(*(const uint4*)((const u16*)p + idx), f); }
  else {
    const float4* q = (const float4*)((const float*)p + idx);
    float4 a = q[0], b = q[1];
    f[0] = a.x; f[1] = a.y; f[2] = a.z; f[3] = a.w;
    f[4] = b.x; f[5] = b.y; f[6] = b.z; f[7] = b.w;
  }
}
static __device__ __forceinline__ float ld1(const void* p, size_t idx, int bf) {
  return bf ? bfbits2f(((const u16*)p)[idx]) : ((const float*)p)[idx];
}
// dual-dtype 8-element load -> packed bf16 (uint4)
static __device__ __forceinline__ uint4 ld8_to_bf(const void* p, size_t idx, int bf) {
  if (bf) return *(const uint4*)((const u16*)p + idx);
  float f[8]; ld8(p, idx, 0, f);
  uint4 u;
  u.x = (uint)f2bf(f[0]) | ((uint)f2bf(f[1]) << 16);
  u.y = (uint)f2bf(f[2]) | ((uint)f2bf(f[3]) << 16);
  u.z = (uint)f2bf(f[4]) | ((uint)f2bf(f[5]) << 16);
  u.w = (uint)f2bf(f[6]) | ((uint)f2bf(f[7]) << 16);
  return u;
}
// async 16B global->LDS (dest: wave-uniform base, HW adds lane*16)
static __device__ __forceinline__ void gll16(const u16* g, u16* l) {
  __builtin_amdgcn_global_load_lds(
      (const __attribute__((address_space(1))) unsigned int*)g,
      (__attribute__((address_space(3))) unsigned int*)l, 16, 0, 0);
}

// ---------------------------------------------------------------------------
// K0: dtype detector (verified).
// ---------------------------------------------------------------------------
__global__ __launch_bounds__(256) void detect_k(const u16* __restrict__ x,
                                                int* __restrict__ mode) {
  __shared__ int wsum[4];
  int t = threadIdx.x;
  int cnt = 0;
  for (int i = 0; i < 8; ++i) {
    uint u = x[(size_t)(t * 8 + i) * 2];
    uint e = (u >> 7) & 0xFFu;
    uint mag = u & 0x7FFFu;
    if (mag == 0 || (e >= 113 && e <= 133)) cnt++;
  }
#pragma unroll
  for (int d = 1; d < 64; d <<= 1) cnt += __shfl_xor(cnt, d);
  if ((t & 63) == 0) wsum[t >> 6] = cnt;
  __syncthreads();
  if (t == 0) mode[0] = ((wsum[0] + wsum[1] + wsum[2] + wsum[3]) > 1024) ? 1 : 0;
}

// ---------------------------------------------------------------------------
// K0b: convert x / qkv_w / proj_w to bf16 (verified round 11).
// ---------------------------------------------------------------------------
#define NX8 442368u   // 4608*768/8
#define NW8 221184u   // 2304*768/8
#define NP8 73728u    // 768*768/8
__global__ __launch_bounds__(256) void convert_k(
    const void* __restrict__ x, const void* __restrict__ qkvw,
    const void* __restrict__ pw, const int* __restrict__ mode,
    u16* __restrict__ xb, u16* __restrict__ wb, u16* __restrict__ pwb)
{
  const int bf = mode[0];
  uint i8 = blockIdx.x * 256 + threadIdx.x;
  if (i8 < NX8) {
    *(uint4*)(xb + (size_t)i8 * 8) = ld8_to_bf(x, (size_t)i8 * 8, bf);
  } else if (i8 < NX8 + NW8) {
    size_t j = i8 - NX8;
    *(uint4*)(wb + j * 8) = ld8_to_bf(qkvw, j * 8, bf);
  } else if (i8 < NX8 + NW8 + NP8) {
    size_t j = i8 - NX8 - NW8;
    *(uint4*)(pwb + j * 8) = ld8_to_bf(pw, j * 8, bf);
  }
}

// ---------------------------------------------------------------------------
// K1: QKV projection — gll16 staging + fused V^T (verified round 13).
// ---------------------------------------------------------------------------
__global__ __launch_bounds__(256) void qkv_gemm_k(
    const u16* __restrict__ Xb, const u16* __restrict__ Wb,
    const void* __restrict__ Bq, const int* __restrict__ mode,
    u16* __restrict__ Q, u16* __restrict__ K, u16* __restrict__ Vt)
{
  __shared__ __align__(16) u16 As[128][32];
  __shared__ __align__(16) u16 Bs[128][32];
  __shared__ __align__(16) u16 Ts[128][72];   // V^T staging (idle for Q/K blocks)
  const int bf = mode[0];
  const int t = threadIdx.x;
  const int w = t >> 6, lane = t & 63, l15 = t & 15, quad = (t >> 4) & 3;
  const int wr = w >> 1, wc = w & 1;
  const int row0 = blockIdx.y << 7, col0 = blockIdx.x << 7;
  const int r4 = lane >> 2, c8 = (lane & 3) << 3;   // staging lane map

  f32x4 zero4 = {0.f, 0.f, 0.f, 0.f};
  f32x4 acc[4][4];
#pragma unroll
  for (int i = 0; i < 4; ++i)
#pragma unroll
    for (int j = 0; j < 4; ++j) acc[i][j] = zero4;

  for (int kt = 0; kt < DIMC; kt += 32) {
    __syncthreads();
    gll16(Xb + (size_t)(row0 + (w << 5) + r4) * DIMC + kt + c8,      &As[(w << 5)][0]);
    gll16(Xb + (size_t)(row0 + (w << 5) + 16 + r4) * DIMC + kt + c8, &As[(w << 5) + 16][0]);
    gll16(Wb + (size_t)(col0 + (w << 5) + r4) * DIMC + kt + c8,      &Bs[(w << 5)][0]);
    gll16(Wb + (size_t)(col0 + (w << 5) + 16 + r4) * DIMC + kt + c8, &Bs[(w << 5) + 16][0]);
    __syncthreads();
    s16x8 af[4], bfr[4];
#pragma unroll
    for (int i = 0; i < 4; ++i)
      af[i] = *(const s16x8*)&As[(wr << 6) + (i << 4) + l15][quad << 3];
#pragma unroll
    for (int j = 0; j < 4; ++j)
      bfr[j] = *(const s16x8*)&Bs[(wc << 6) + (j << 4) + l15][quad << 3];
#pragma unroll
    for (int i = 0; i < 4; ++i)
#pragma unroll
      for (int j = 0; j < 4; ++j)
        acc[i][j] = MFMA16(af[i], bfr[j], acc[i][j]);
  }

  if (blockIdx.x < 12) {
    // Q/K path: scatter per element (verified)
#pragma unroll
    for (int jt = 0; jt < 4; ++jt) {
      int col = col0 + (wc << 6) + (jt << 4) + l15;     // 0..1535
      int which = col / DIMC;
      int rem = col - which * DIMC;
      int head = rem >> 6, d = rem & 63;
      float bv = ld1(Bq, col, bf);
      u16* dst = (which == 0) ? Q : K;
#pragma unroll
      for (int i = 0; i < 4; ++i)
#pragma unroll
        for (int r = 0; r < 4; ++r) {
          int mrow = row0 + (wr << 6) + (i << 4) + (quad << 2) + r;
          int b_ = (mrow >= NQ) ? 1 : 0;
          int n = mrow - b_ * NQ;
          dst[(((size_t)(b_ * NHEAD + head)) * NQ + n) * HD + d] = f2bf(acc[i][jt][r] + bv);
        }
    }
  } else {
    // V path: transpose to Vt [bh][d][n] via LDS, two 64-col halves.
    int b_ = (row0 >= NQ) ? 1 : 0;
    int n0 = row0 - b_ * NQ;
#pragma unroll
    for (int h = 0; h < 2; ++h) {
      if (wc == h) {
#pragma unroll
        for (int jt = 0; jt < 4; ++jt) {
          int coll = (jt << 4) + l15;                  // 0..63 within half
          float bv = ld1(Bq, col0 + (h << 6) + coll, bf);
#pragma unroll
          for (int i = 0; i < 4; ++i)
#pragma unroll
            for (int r = 0; r < 4; ++r) {
              int tok = (wr << 6) + (i << 4) + (quad << 2) + r;   // 0..127
              Ts[tok][coll] = f2bf(acc[i][jt][r] + bv);
            }
        }
      }
      __syncthreads();
      int head = ((col0 - 1536) >> 6) + h;
      u16* dst = Vt + ((size_t)(b_ * NHEAD + head) * HD) * NQ + n0;
      int d = t >> 2, ch = (t & 3) << 5;               // 64 d x 4 token-chunks
#pragma unroll
      for (int c4 = 0; c4 < 4; ++c4) {
        u16 tmp[8];
#pragma unroll
        for (int j = 0; j < 8; ++j) tmp[j] = Ts[ch + (c4 << 3) + j][d];
        *(uint4*)(dst + (size_t)d * NQ + ch + (c4 << 3)) = *(uint4*)tmp;
      }
      __syncthreads();
    }
  }
}

// ---------------------------------------------------------------------------
// K1b: bias precompute as MFMA GEMM (round 7 body, r12 configuration —
// NO log2e scaling; reverted with attn).
// ---------------------------------------------------------------------------
__global__ __launch_bounds__(256) void bias_gemm_k(
    const u16* __restrict__ Qw,
    const void* __restrict__ rph, const void* __restrict__ rpw,
    const int* __restrict__ mode,
    u16* __restrict__ Bh_g, u16* __restrict__ Bw_g)
{
  __shared__ __align__(16) u16 As[128][72];
  __shared__ __align__(16) u16 Bs[192][72];
  const int bf = mode[0];
  const int t = threadIdx.x;
  const int w = t >> 6, l15 = t & 15, quad = (t >> 4) & 3;
  const int wr = w >> 1, wc = w & 1;
  const int blk = blockIdx.x;          // 0..431
  const int bhd = blk / 18;
  const int row0 = (blk - bhd * 18) << 7;

  {
    int lr = t >> 1, lk = (t & 1) << 5;
    const u16* src = Qw + ((size_t)bhd * NQ + row0 + lr) * HD + lk;
    *(uint4*)&As[lr][lk]      = *(const uint4*)(src);
    *(uint4*)&As[lr][lk + 8]  = *(const uint4*)(src + 8);
    *(uint4*)&As[lr][lk + 16] = *(const uint4*)(src + 16);
    *(uint4*)&As[lr][lk + 24] = *(const uint4*)(src + 24);
  }
  for (int e = t; e < 384; e += 256) {
    int row = e >> 1, k32 = (e & 1) << 5;
    int tab = (row >= 96) ? 1 : 0;
    int r2 = row - (tab ? 96 : 0);
    if (r2 > 94) r2 = 0;
    const void* src = tab ? rpw : rph;
    *(uint4*)&Bs[row][k32]      = ld8_to_bf(src, (size_t)r2 * HD + k32, bf);
    *(uint4*)&Bs[row][k32 + 8]  = ld8_to_bf(src, (size_t)r2 * HD + k32 + 8, bf);
    *(uint4*)&Bs[row][k32 + 16] = ld8_to_bf(src, (size_t)r2 * HD + k32 + 16, bf);
    *(uint4*)&Bs[row][k32 + 24] = ld8_to_bf(src, (size_t)r2 * HD + k32 + 24, bf);
  }
  __syncthreads();

  f32x4 zero4 = {0.f, 0.f, 0.f, 0.f};
  f32x4 acc[4][6];
#pragma unroll
  for (int i = 0; i < 4; ++i)
#pragma unroll
    for (int j = 0; j < 6; ++j) acc[i][j] = zero4;

#pragma unroll
  for (int ks = 0; ks < 2; ++ks) {
    s16x8 af[4], bfr[6];
#pragma unroll
    for (int i = 0; i < 4; ++i)
      af[i] = *(const s16x8*)&As[(wr << 6) + (i << 4) + l15][(ks << 5) + (quad << 3)];
#pragma unroll
    for (int j = 0; j < 6; ++j)
      bfr[j] = *(const s16x8*)&Bs[wc * 96 + (j << 4) + l15][(ks << 5) + (quad << 3)];
#pragma unroll
    for (int i = 0; i < 4; ++i)
#pragma unroll
      for (int j = 0; j < 6; ++j)
        acc[i][j] = MFMA16(af[i], bfr[j], acc[i][j]);
  }

#pragma unroll
  for (int jt = 0; jt < 6; ++jt) {
    int col = wc * 96 + (jt << 4) + l15;     // 0..191
    int tab = (col >= 96) ? 1 : 0;
    int j = col - (tab ? 96 : 0);
    if (j >= 95) continue;
    u16* dstT = tab ? Bw_g : Bh_g;
#pragma unroll
    for (int i = 0; i < 4; ++i)
#pragma unroll
      for (int r = 0; r < 4; ++r) {
        int n = row0 + (wr << 6) + (i << 4) + (quad << 2) + r;
        int qh = (n * 10923) >> 19;
        int coord = tab ? (n - qh * 48) : qh;
        int c = coord + 47 - j;
        if (c >= 0 && c < 48)
          dstT[((size_t)bhd * 48 + c) * NQ + n] = f2h(acc[i][jt][r]);
      }
  }
}

// ---------------------------------------------------------------------------
// K2: MFMA flash attention — EXACT round-12 configuration (152.7 µs, VGPR
// 120, verified). r13's setprio+exp2 pushed VGPR to 144 (past the 128
// wave-class cliff) and regressed; reverted.
// ---------------------------------------------------------------------------
#define ATILE(KB, KN, T0, PREF, KM) do {                                      \
    f32x4 acc_s[2][4];                                                        \
    _Pragma("unroll")                                                         \
    for (int nc = 0; nc < 4; ++nc) {                                          \
      f32x4 a0 = MFMA16(KB[2*nc], qa0[0], zero4);                             \
      acc_s[0][nc] = MFMA16(KB[2*nc+1], qa1[0], a0);                          \
      f32x4 a1 = MFMA16(KB[2*nc], qa0[1], zero4);                             \
      acc_s[1][nc] = MFMA16(KB[2*nc+1], qa1[1], a1);                          \
    }                                                                         \
    if (PREF) {                                                               \
      _Pragma("unroll")                                                       \
      for (int nc = 0; nc < 4; ++nc) {                                        \
        const u16* kp_ = kbase + (size_t)((T0) + 64 + (nc << 4) + l15) * HD + (quad << 3); \
        KN[2*nc]   = *(const s16x8*)(kp_);                                    \
        KN[2*nc+1] = *(const s16x8*)(kp_ + 32);                               \
      }                                                                       \
    }                                                                         \
    int kh0 = ((T0) * 10923) >> 19;                                           \
    int thr = (kh0 + 1) * 48 - (T0);                                          \
    uint Wq[2][8];                                                            \
    _Pragma("unroll")                                                         \
    for (int g = 0; g < 2; ++g) {                                             \
      int qrl = (w << 5) + (g << 4) + l15;                                    \
      float bh0v = h2f(BhL[kh0][qrl]);                                        \
      float bh1v = h2f(BhL[kh0 + 1][qrl]);                                    \
      float sum = 0.f;                                                        \
      _Pragma("unroll")                                                       \
      for (int nc = 0; nc < 4; ++nc) {                                        \
        int bnc = (KM) + (nc << 4);                                           \
        bnc = (bnc >= 48) ? bnc - 48 : bnc;                                   \
        uint2 pv = *(const uint2*)&BwL[qrl][bnc + (quad << 2)];               \
        float b0 = h2f((u16)(pv.x & 0xFFFFu));                                \
        float b1 = h2f((u16)(pv.x >> 16));                                    \
        float b2 = h2f((u16)(pv.y & 0xFFFFu));                                \
        float b3 = h2f((u16)(pv.y >> 16));                                    \
        int kl = (nc << 4) + (quad << 2);                                     \
        float e0 = __expf(acc_s[g][nc][0] * scale + ((kl     >= thr) ? bh1v : bh0v) + b0); \
        float e1 = __expf(acc_s[g][nc][1] * scale + ((kl + 1 >= thr) ? bh1v : bh0v) + b1); \
        float e2 = __expf(acc_s[g][nc][2] * scale + ((kl + 2 >= thr) ? bh1v : bh0v) + b2); \
        float e3 = __expf(acc_s[g][nc][3] * scale + ((kl + 3 >= thr) ? bh1v : bh0v) + b3); \
        sum += (e0 + e1) + (e2 + e3);                                         \
        Wq[g][2*nc]   = (uint)f2bf(e0) | ((uint)f2bf(e1) << 16);              \
        Wq[g][2*nc+1] = (uint)f2bf(e2) | ((uint)f2bf(e3) << 16);              \
      }                                                                       \
      l_st[g] += sum;                                                         \
    }                                                                         \
    _Pragma("unroll")                                                         \
    for (int h = 0; h < 2; ++h) {                                             \
      s16x8 vb[4];                                                            \
      _Pragma("unroll")                                                       \
      for (int nc = 0; nc < 4; ++nc)                                          \
        vb[nc] = *(const s16x8*)(vtbase + (size_t)((nc << 4) + l15) * NQ      \
                                 + (T0) + (h << 5) + (quad << 3));            \
      _Pragma("unroll")                                                       \
      for (int g = 0; g < 2; ++g) {                                           \
        uint e0 = __shfl(Wq[g][4*h+0], srcA), e1 = __shfl(Wq[g][4*h+1], srcA); \
        uint e2 = __shfl(Wq[g][4*h+2], srcA), e3 = __shfl(Wq[g][4*h+3], srcA); \
        uint g0 = __shfl(Wq[g][4*h+0], srcB), g1 = __shfl(Wq[g][4*h+1], srcB); \
        uint g2 = __shfl(Wq[g][4*h+2], srcB), g3 = __shfl(Wq[g][4*h+3], srcB); \
        union { uint u[4]; s16x8 v; } pf;                                     \
        pf.u[0] = hi ? e2 : e0; pf.u[1] = hi ? e3 : e1;                       \
        pf.u[2] = hi ? g2 : g0; pf.u[3] = hi ? g3 : g1;                       \
        _Pragma("unroll")                                                     \
        for (int nc = 0; nc < 4; ++nc)                                        \
          acc_o[g][nc] = MFMA16(pf.v, vb[nc], acc_o[g][nc]);                  \
      }                                                                       \
    }                                                                         \
  } while (0)

__global__ __launch_bounds__(256) void attn_k(
    const u16* __restrict__ Qw, const u16* __restrict__ Kw,
    const u16* __restrict__ Vtg,
    const u16* __restrict__ Bh_g, const u16* __restrict__ Bw_g,
    int S, float* __restrict__ Opart, float* __restrict__ Lpart,
    u16* __restrict__ Aout)
{
  __shared__ __align__(16) u16 BhL[48][128];  // fp16 [kh][local qrow]
  __shared__ __align__(16) u16 BwL[128][52];  // fp16 [local qrow][kw]

  const int bid = blockIdx.x;
  const int xcd = bid & 7;
  const int local = bid >> 3;            // [0, 54*S)
  const int per_head = 18 * S;
  const int head_l = local / per_head;   // 0..2
  const int rem = local - head_l * per_head;
  const int qb = rem / S;                // 0..17 (128-row q block)
  const int z = rem - qb * S;
  const int bhd = xcd * 3 + head_l;
  const int q0 = qb << 7;
  const int span = NQ / S;               // 2304/1152/768 — all mult of 128
  const int kt_lo = z * span, kt_hi = kt_lo + span;

  const int t = threadIdx.x;
  const int w = t >> 6, l15 = t & 15, quad = (t >> 4) & 3;
  const float scale = 0.125f;   // 64^-0.5

  const u16* kbase  = Kw  + (size_t)bhd * NQ * HD;
  const u16* vtbase = Vtg + (size_t)bhd * HD * NQ;
  const int q0w = q0 + (w << 5);         // wave's 32-row base (global token)

  for (int e = t; e < 768; e += 256) {
    int c = e >> 4;                       // kh/kw 0..47
    int off = (e & 15) << 3;              // qrow 0..120 step 8
    size_t gi = ((size_t)bhd * 48 + c) * NQ + q0 + off;
    *(uint4*)&BhL[c][off] = *(const uint4*)(Bh_g + gi);
    uint4 wv = *(const uint4*)(Bw_g + gi);
    u16 vals[8];
    vals[0] = wv.x & 0xFFFFu; vals[1] = wv.x >> 16;
    vals[2] = wv.y & 0xFFFFu; vals[3] = wv.y >> 16;
    vals[4] = wv.z & 0xFFFFu; vals[5] = wv.z >> 16;
    vals[6] = wv.w & 0xFFFFu; vals[7] = wv.w >> 16;
#pragma unroll
    for (int j = 0; j < 8; ++j) BwL[off + j][c] = vals[j];
  }

  s16x8 qa0[2], qa1[2];
#pragma unroll
  for (int g = 0; g < 2; ++g) {
    const u16* qfrag = Qw + ((size_t)bhd * NQ + q0w + (g << 4) + l15) * HD + (quad << 3);
    qa0[g] = *(const s16x8*)(qfrag);
    qa1[g] = *(const s16x8*)(qfrag + 32);
  }

  s16x8 kbA[8], kbB[8];
#pragma unroll
  for (int nc = 0; nc < 4; ++nc) {
    const u16* kp = kbase + (size_t)(kt_lo + (nc << 4) + l15) * HD + (quad << 3);
    kbA[2*nc]   = *(const s16x8*)(kp);
    kbA[2*nc+1] = *(const s16x8*)(kp + 32);
  }

  __syncthreads();   // bias tables visible

  f32x4 zero4 = {0.f, 0.f, 0.f, 0.f};
  f32x4 acc_o[2][4];
#pragma unroll
  for (int g = 0; g < 2; ++g)
#pragma unroll
    for (int nc = 0; nc < 4; ++nc) acc_o[g][nc] = zero4;
  float l_st[2] = {0.f, 0.f};
  const int srcA = ((quad & 1) << 5) + l15;
  const int srcB = srcA + 16;
  const int hi = quad >> 1;
  int km = 0;         // kt0 % 48; kt_lo % 48 == 0 for all splits

  for (int kt0 = kt_lo; kt0 < kt_hi; kt0 += 128) {
    ATILE(kbA, kbB, kt0, 1, km);
    km += 16; if (km >= 48) km -= 48;
    int pref2 = (kt0 + 128) < kt_hi;
    ATILE(kbB, kbA, kt0 + 64, pref2, km);
    km += 16; if (km >= 48) km -= 48;
  }

#pragma unroll
  for (int g = 0; g < 2; ++g) {
    float lg = l_st[g];
    lg += __shfl_xor(lg, 16);
    lg += __shfl_xor(lg, 32);
    if (S > 1) {
      float* Op = Opart + ((size_t)(z * HEADS + bhd) * NQ + q0) * HD;
#pragma unroll
      for (int r = 0; r < 4; ++r) {
        int row = (w << 5) + (g << 4) + (quad << 2) + r;
#pragma unroll
        for (int nc = 0; nc < 4; ++nc)
          Op[(size_t)row * HD + (nc << 4) + l15] = acc_o[g][nc][r];
      }
      if (quad == 0)
        Lpart[(size_t)(z * HEADS + bhd) * NQ + q0w + (g << 4) + l15] = lg;
    } else {
      int b_ = bhd / NHEAD, head = bhd - b_ * NHEAD;
      float invl = 1.f / lg;
      int bsrc = (quad << 4) + (quad << 2);
#pragma unroll
      for (int r = 0; r < 4; ++r) {
        float inv = __shfl(invl, bsrc + r);   // lane with l15 == 4*quad+r
        int token = q0 + (w << 5) + (g << 4) + (quad << 2) + r;
        u16* dst = Aout + ((size_t)b_ * NQ + token) * DIMC + (head << 6);
#pragma unroll
        for (int nc = 0; nc < 4; ++nc)
          dst[(nc << 4) + l15] = f2bf(acc_o[g][nc][r] * inv);
      }
    }
  }
}

// ---------------------------------------------------------------------------
// K2b: combine split-K partials (verified).
// ---------------------------------------------------------------------------
__global__ __launch_bounds__(256) void combine_k(
    const float* __restrict__ Op, const float* __restrict__ Lp,
    int S, u16* __restrict__ Aout)
{
  int idx = blockIdx.x * 256 + threadIdx.x;   // 0 .. 884735
  int m = idx / 192;
  int cq = idx - m * 192;
  int ccol = cq << 2;
  int head = ccol >> 6, d0 = ccol & 63;
  int b_ = (m >= NQ) ? 1 : 0;
  int n = m - b_ * NQ;
  int bh = b_ * NHEAD + head;
  float ox = 0.f, oy = 0.f, oz = 0.f, ow = 0.f, ls = 0.f;
  for (int zz = 0; zz < S; ++zz) {
    const float* ob = Op + ((size_t)(zz * HEADS + bh) * NQ + n) * HD + d0;
    float4 v = *(const float4*)ob;
    ox += v.x; oy += v.y; oz += v.z; ow += v.w;
    ls += Lp[(size_t)(zz * HEADS + bh) * NQ + n];
  }
  float inv = 1.f / ls;
  u16* dst = Aout + (size_t)m * DIMC + ccol;
  dst[0] = f2bf(ox * inv); dst[1] = f2bf(oy * inv);
  dst[2] = f2bf(oz * inv); dst[3] = f2bf(ow * inv);
}

// ---------------------------------------------------------------------------
// K3: output projection — gll16 staging (r12, verified).
// ---------------------------------------------------------------------------
__global__ __launch_bounds__(256) void proj_gemm_k(
    const u16* __restrict__ A, const u16* __restrict__ Wb,
    const void* __restrict__ Bp, const int* __restrict__ mode,
    void* __restrict__ Out)
{
  __shared__ __align__(16) u16 As[128][32];
  __shared__ __align__(16) u16 Bs[128][32];
  const int bf = mode[0];
  const int t = threadIdx.x;
  const int w = t >> 6, lane = t & 63, l15 = t & 15, quad = (t >> 4) & 3;
  const int wr = w >> 1, wc = w & 1;
  const int row0 = blockIdx.y << 7, col0 = blockIdx.x << 7;
  const int r4 = lane >> 2, c8 = (lane & 3) << 3;

  f32x4 zero4 = {0.f, 0.f, 0.f, 0.f};
  f32x4 acc[4][4];
#pragma unroll
  for (int i = 0; i < 4; ++i)
#pragma unroll
    for (int j = 0; j < 4; ++j) acc[i][j] = zero4;

  for (int kt = 0; kt < DIMC; kt += 32) {
    __syncthreads();
    gll16(A + (size_t)(row0 + (w << 5) + r4) * DIMC + kt + c8,       &As[(w << 5)][0]);
    gll16(A + (size_t)(row0 + (w << 5) + 16 + r4) * DIMC + kt + c8,  &As[(w << 5) + 16][0]);
    gll16(Wb + (size_t)(col0 + (w << 5) + r4) * DIMC + kt + c8,      &Bs[(w << 5)][0]);
    gll16(Wb + (size_t)(col0 + (w << 5) + 16 + r4) * DIMC + kt + c8, &Bs[(w << 5) + 16][0]);
    __syncthreads();
    s16x8 af[4], bfr[4];
#pragma unroll
    for (int i = 0; i < 4; ++i)
      af[i] = *(const s16x8*)&As[(wr << 6) + (i << 4) + l15][quad << 3];
#pragma unroll
    for (int j = 0; j < 4; ++j)
      bfr[j] = *(const s16x8*)&Bs[(wc << 6) + (j << 4) + l15][quad << 3];
#pragma unroll
    for (int i = 0; i < 4; ++i)
#pragma unroll
      for (int j = 0; j < 4; ++j)
        acc[i][j] = MFMA16(af[i], bfr[j], acc[i][j]);
  }

#pragma unroll
  for (int jt = 0; jt < 4; ++jt) {
    int col = col0 + (wc << 6) + (jt << 4) + l15;
    float bv = ld1(Bp, col, bf);
#pragma unroll
    for (int i = 0; i < 4; ++i)
#pragma unroll
      for (int r = 0; r < 4; ++r) {
        int mrow = row0 + (wr << 6) + (i << 4) + (quad << 2) + r;
        float val = acc[i][jt][r] + bv;
        size_t off = (size_t)mrow * DIMC + col;
        if (bf) ((u16*)Out)[off] = f2bf(val);
        else    ((float*)Out)[off] = val;
      }
  }
}

// ---------------------------------------------------------------------------
extern "C" void kernel_launch(void* const* d_in, const int* in_sizes, int n_in,
                              void* d_out, int out_size, void* d_ws, size_t ws_size,
                              hipStream_t stream)
{
  const void* x    = d_in[0];   // (2,48,48,768)
  const void* rph  = d_in[1];   // (95,64)
  const void* rpw  = d_in[2];   // (95,64)
  const void* qkvw = d_in[3];   // (2304,768)
  const void* qkvb = d_in[4];   // (2304,)
  const void* pw   = d_in[5];   // (768,768)
  const void* pb   = d_in[6];   // (768,)

  int* mode = (int*)d_ws;
  const size_t qkv_elems = (size_t)HEADS * NQ * HD;   // 3,538,944
  const size_t NXe = (size_t)MROWS * DIMC;            // 3,538,944
  const size_t NWe = (size_t)3 * DIMC * DIMC;         // 1,769,472
  const size_t NPe = (size_t)DIMC * DIMC;             //   589,824
  u16* q    = (u16*)((char*)d_ws + 16);
  u16* k    = q + qkv_elems;
  u16* vt   = k + qkv_elems;
  u16* aout = vt + qkv_elems;
  u16* pwb  = aout + qkv_elems;
  const size_t biasElems = (size_t)HEADS * 48 * NQ;   // 2,654,208 per table
  u16* bh_g = pwb + NPe;
  u16* bw_g = bh_g + biasElems;
  char* R   = (char*)(bw_g + biasElems);
  const size_t baseR = (size_t)((char*)R - (char*)d_ws);
  u16* xb = (u16*)R;
  u16* wb = xb + NXe;
  const size_t needXW = (NXe + NWe) * 2;              // 10,616,832
  const size_t perO = (size_t)HEADS * NQ * HD * 4;    // 14,155,776
  const size_t perL = (size_t)HEADS * NQ * 4;         //    221,184

  int S = 1;
  size_t n3 = 3 * (perO + perL), n2 = 2 * (perO + perL);
  if (ws_size >= baseR + (n3 > needXW ? n3 : needXW)) S = 3;
  else if (ws_size >= baseR + (n2 > needXW ? n2 : needXW)) S = 2;
  float* opart = (float*)R;
  float* lpart = (float*)(R + (size_t)S * perO);

  detect_k<<<1, 256, 0, stream>>>((const u16*)x, mode);
  convert_k<<<dim3(2880), 256, 0, stream>>>(x, qkvw, pw, mode, xb, wb, pwb);
  qkv_gemm_k<<<dim3(18, 36), 256, 0, stream>>>(xb, wb, qkvb, mode, q, k, vt);
  bias_gemm_k<<<dim3(432), 256, 0, stream>>>(q, rph, rpw, mode, bh_g, bw_g);
  attn_k<<<dim3(432 * S), 256, 0, stream>>>(q, k, vt, bh_g, bw_g,
                                            S, opart, lpart, aout);
  if (S > 1)
    combine_k<<<dim3(3456), 256, 0, stream>>>(opart, lpart, S, aout);
  proj_gemm_k<<<dim3(6, 36), 256, 0, stream>>>(aout, pwb, pb, mode, d_out);
}